// Round 1
// baseline (2234.854 us; speedup 1.0000x reference)
//
#include <hip/hip_runtime.h>
#include <float.h>
#include <math.h>

// Problem constants (fixed shapes from setup_inputs)
constexpr int B = 8, N1 = 400, N2 = 64, NP = N1 + N2, F = 54, C = 128;
constexpr int RR = 40;        // lattice size after slicing
constexpr int RG = 41;        // scatter grid (includes dump cell at 40,40,40)
constexpr int MAXOCC = NP;            // max occupied voxels per batch
constexpr int MAXACT = NP * 27;       // max active (dilated) voxels per batch

constexpr size_t align256(size_t x) { return (x + 255) & ~(size_t)255; }

// Workspace layout
constexpr size_t OFF_SUB  = 0;                                   // B*3 f32
constexpr size_t OFF_WIN  = align256(OFF_SUB  + (size_t)B*3*4);  // B*41^3 i32
constexpr size_t SZ_WIN   = (size_t)B*RG*RG*RG*4;
constexpr size_t OFF_SLOT = align256(OFF_WIN  + SZ_WIN);         // B*40^3 i32
constexpr size_t SZ_SLOT  = (size_t)B*RR*RR*RR*4;
constexpr size_t OFF_ACTG = align256(OFF_SLOT + SZ_SLOT);        // B*40^3 i32
constexpr size_t OFF_OCNT = align256(OFF_ACTG + SZ_SLOT);        // B i32
constexpr size_t OFF_ACNT = align256(OFF_OCNT + (size_t)B*4);    // B i32
constexpr size_t OFF_OCC  = align256(OFF_ACNT + (size_t)B*4);    // B*MAXOCC i32 (packed coords)
constexpr size_t OFF_ALST = align256(OFF_OCC  + (size_t)B*MAXOCC*4); // B*MAXACT i32
constexpr size_t OFF_FEAT = align256(OFF_ALST + (size_t)B*MAXACT*4); // B*MAXOCC*F f32
constexpr size_t OFF_WT   = align256(OFF_FEAT + (size_t)B*MAXOCC*F*4); // 27*F*C f32
constexpr size_t OFF_CSUM = align256(OFF_WT   + (size_t)27*F*C*4);     // C f32
constexpr size_t OFF_PART = align256(OFF_CSUM + (size_t)C*4);          // B f64

// ---------------- K1: bounding-box center (sub) ----------------
__global__ void k_bbox(const float* __restrict__ pos1,
                       const float* __restrict__ valid1,
                       float* __restrict__ sub) {
    int b = blockIdx.x;
    int t = threadIdx.x;  // 64 threads = 1 wave
    float bmax[3] = {-FLT_MAX, -FLT_MAX, -FLT_MAX};
    float bmin[3] = { FLT_MAX,  FLT_MAX,  FLT_MAX};
    for (int n = t; n < N1; n += 64) {
        float v = valid1[b*N1 + n];
        const float* pp = pos1 + ((size_t)b*N1 + n)*3;
        float p0 = pp[0]*v, p1 = pp[1]*v, p2 = pp[2]*v;
        float s = p0 + p1 + p2;
        bool nz = (s == 0.0f);
        float amax = nz ? -10000000000.0f : 0.0f;
        float amin = nz ?  10000000000.0f : 0.0f;
        bmax[0] = fmaxf(bmax[0], p0 + amax);
        bmax[1] = fmaxf(bmax[1], p1 + amax);
        bmax[2] = fmaxf(bmax[2], p2 + amax);
        bmin[0] = fminf(bmin[0], p0 + amin);
        bmin[1] = fminf(bmin[1], p1 + amin);
        bmin[2] = fminf(bmin[2], p2 + amin);
    }
    #pragma unroll
    for (int off = 32; off; off >>= 1) {
        #pragma unroll
        for (int d = 0; d < 3; d++) {
            bmax[d] = fmaxf(bmax[d], __shfl_xor(bmax[d], off));
            bmin[d] = fminf(bmin[d], __shfl_xor(bmin[d], off));
        }
    }
    if (t == 0) {
        #pragma unroll
        for (int d = 0; d < 3; d++)
            sub[b*3 + d] = bmin[d] + (bmax[d] - bmin[d]) / 2.0f;
    }
}

// helper: compute voxel index for global point n (n<N1 -> pos1 else pos2)
__device__ inline void point_idx(const float* pos1, const float* valid1,
                                 const float* pos2, const float* valid2,
                                 const float* sub, int b, int n,
                                 int& ix, int& iy, int& iz, bool& inb, float& vout) {
    float px, py, pz, v;
    if (n < N1) {
        v = valid1[b*N1 + n];
        const float* p = pos1 + ((size_t)b*N1 + n)*3;
        px = p[0]*v; py = p[1]*v; pz = p[2]*v;
    } else {
        int m = n - N1;
        v = valid2[b*N2 + m];
        const float* p = pos2 + ((size_t)b*N2 + m)*3;
        px = p[0]*v; py = p[1]*v; pz = p[2]*v;
    }
    const float* sb = sub + b*3;
    ix = (int)floorf((px - sb[0] + 10.0f) / 0.5f);
    iy = (int)floorf((py - sb[1] + 10.0f) / 0.5f);
    iz = (int)floorf((pz - sb[2] + 10.0f) / 0.5f);
    inb = (ix >= 0 && ix <= RR-1 && iy >= 0 && iy <= RR-1 && iz >= 0 && iz <= RR-1);
    vout = v;
}

// ---------------- K2: winner scatter (last-write-wins via atomicMax) ----------------
__global__ void k_scatter(const float* __restrict__ pos1, const float* __restrict__ valid1,
                          const float* __restrict__ pos2, const float* __restrict__ valid2,
                          const float* __restrict__ sub, int* __restrict__ winner) {
    int g = blockIdx.x*blockDim.x + threadIdx.x;
    if (g >= B*NP) return;
    int b = g / NP, n = g % NP;
    int ix, iy, iz; bool inb; float v;
    point_idx(pos1, valid1, pos2, valid2, sub, b, n, ix, iy, iz, inb, v);
    int x = inb ? ix : RR, y = inb ? iy : RR, z = inb ? iz : RR;
    int cell = (x*RG + y)*RG + z;
    atomicMax(&winner[(size_t)b*RG*RG*RG + cell], n);
}

// ---------------- K3: claim winners, compact occupied list + features ----------------
__global__ void k_claim(const float* __restrict__ pos1, const float* __restrict__ valid1,
                        const float* __restrict__ pos2, const float* __restrict__ valid2,
                        const float* __restrict__ h1, const float* __restrict__ h2,
                        const float* __restrict__ sub, const int* __restrict__ winner,
                        int* __restrict__ slotGrid, int* __restrict__ occCount,
                        int* __restrict__ occCoords, float* __restrict__ feats) {
    int g = blockIdx.x*blockDim.x + threadIdx.x;
    if (g >= B*NP) return;
    int b = g / NP, n = g % NP;
    int ix, iy, iz; bool inb; float v;
    point_idx(pos1, valid1, pos2, valid2, sub, b, n, ix, iy, iz, inb, v);
    if (!inb) return;  // dump cell (40,40,40) is sliced off
    int cell = (ix*RG + iy)*RG + iz;
    if (winner[(size_t)b*RG*RG*RG + cell] != n) return;
    int slot = atomicAdd(&occCount[b], 1);
    slotGrid[(size_t)b*RR*RR*RR + (ix*RR + iy)*RR + iz] = slot;
    occCoords[b*MAXOCC + slot] = (ix << 12) | (iy << 6) | iz;
    const float* h = (n < N1) ? (h1 + ((size_t)b*N1 + n)*F)
                              : (h2 + ((size_t)b*N2 + (n - N1))*F);
    float* fo = feats + ((size_t)b*MAXOCC + slot)*F;
    for (int f = 0; f < F; f++) fo[f] = h[f] * v;
}

// ---------------- K4: dilate occupied by +-1 Chebyshev -> active list ----------------
__global__ void k_dilate(const int* __restrict__ occCount, const int* __restrict__ occCoords,
                         int* __restrict__ activeGrid, int* __restrict__ activeCount,
                         int* __restrict__ activeList) {
    int g = blockIdx.x*blockDim.x + threadIdx.x;
    if (g >= B*MAXOCC*27) return;
    int b = g / (MAXOCC*27);
    int rem = g % (MAXOCC*27);
    int s = rem / 27, k = rem % 27;
    if (s >= occCount[b]) return;
    int pc = occCoords[b*MAXOCC + s];
    int x = pc >> 12, y = (pc >> 6) & 63, z = pc & 63;
    int nx = x + k/9 - 1, ny = y + (k/3)%3 - 1, nz = z + k%3 - 1;
    if (nx < 0 || nx >= RR || ny < 0 || ny >= RR || nz < 0 || nz >= RR) return;
    size_t lin = (size_t)b*RR*RR*RR + (nx*RR + ny)*RR + nz;
    if (atomicExch(&activeGrid[lin], 1) == 0) {
        int a = atomicAdd(&activeCount[b], 1);
        activeList[b*MAXACT + a] = (nx << 12) | (ny << 6) | nz;
    }
}

// ---------------- K5: transpose conv_w (O,F,27) -> Wt (27,F,O) for coalescing ----------------
__global__ void k_wt(const float* __restrict__ conv_w, float* __restrict__ Wt) {
    int g = blockIdx.x*blockDim.x + threadIdx.x;
    if (g >= 27*F*C) return;
    int o = g & (C-1);
    int rest = g >> 7;       // C==128
    int f = rest % F, s = rest / F;
    Wt[g] = conv_w[((size_t)o*F + f)*27 + s];
}

// ---------------- K6: per-channel fc_w sums (for the ReLU(bias) background) ----------------
__global__ void k_chansum(const float* __restrict__ fc_w, float* __restrict__ chansum) {
    int o = blockIdx.x;
    float s = 0.0f;
    for (int i = threadIdx.x; i < RR*RR*RR; i += 256)
        s += fc_w[(size_t)o*RR*RR*RR + i];
    #pragma unroll
    for (int off = 32; off; off >>= 1) s += __shfl_xor(s, off);
    __shared__ float red[4];
    if ((threadIdx.x & 63) == 0) red[threadIdx.x >> 6] = s;
    __syncthreads();
    if (threadIdx.x == 0) chansum[o] = red[0] + red[1] + red[2] + red[3];
}

// ---------------- K7: sparse conv + relu-diff + fc dot, per active voxel ----------------
__global__ __launch_bounds__(128)
void k_conv(const int* __restrict__ slotGrid, const float* __restrict__ feats,
            const int* __restrict__ activeList, const int* __restrict__ activeCount,
            const float* __restrict__ Wt, const float* __restrict__ conv_b,
            const float* __restrict__ fc_w, double* __restrict__ partial) {
    int b = blockIdx.y;
    int a = blockIdx.x;
    if (a >= activeCount[b]) return;
    int o = threadIdx.x;  // channel

    __shared__ int ns;
    __shared__ int slist[27];
    __shared__ int sstencil[27];
    if (o == 0) ns = 0;
    __syncthreads();

    int pc = activeList[b*MAXACT + a];
    int x0 = pc >> 12, y0 = (pc >> 6) & 63, z0 = pc & 63;

    if (o < 27) {
        int dp = o/9, dq = (o/3)%3, dr = o%3;
        // conv-output (p,q,r) maps to lattice (x=p, y=39-q, z=39-r);
        // stencil tap (p+dp-1, q+dq-1, r+dr-1) -> lattice (x0+dp-1, y0+1-dq, z0+1-dr)
        int nx = x0 + dp - 1, ny = y0 + 1 - dq, nz = z0 + 1 - dr;
        if (nx >= 0 && nx < RR && ny >= 0 && ny < RR && nz >= 0 && nz < RR) {
            int sl = slotGrid[(size_t)b*RR*RR*RR + (nx*RR + ny)*RR + nz];
            if (sl >= 0) { int p = atomicAdd(&ns, 1); slist[p] = sl; sstencil[p] = o; }
        }
    }
    __syncthreads();

    float acc = 0.0f;
    int cnt = ns;
    for (int e = 0; e < cnt; e++) {
        int sl = slist[e], s = sstencil[e];
        const float* fv = feats + ((size_t)b*MAXOCC + sl)*F;
        const float* wv = Wt + (size_t)s*F*C + o;
        #pragma unroll
        for (int f = 0; f < F; f++) acc = fmaf(fv[f], wv[(size_t)f*C], acc);
    }
    float bo = conv_b[o];
    float out = fmaxf(acc + bo, 0.0f) - fmaxf(bo, 0.0f);
    int flat = x0*1600 + (RR-1 - y0)*RR + (RR-1 - z0);
    float w = fc_w[(size_t)o*RR*RR*RR + flat];
    float csum = out * w;

    #pragma unroll
    for (int off = 32; off; off >>= 1) csum += __shfl_xor(csum, off);
    __shared__ float wsum[2];
    if ((o & 63) == 0) wsum[o >> 6] = csum;
    __syncthreads();
    if (o == 0) atomicAdd(&partial[b], (double)(wsum[0] + wsum[1]));
}

// ---------------- K8: finalize ----------------
__global__ void k_final(const float* __restrict__ chansum, const float* __restrict__ conv_b,
                        const float* __restrict__ fc_b, const double* __restrict__ partial,
                        float* __restrict__ out) {
    int o = threadIdx.x;  // 128 threads
    float v = fmaxf(conv_b[o], 0.0f) * chansum[o];
    #pragma unroll
    for (int off = 32; off; off >>= 1) v += __shfl_xor(v, off);
    __shared__ float red[2];
    if ((o & 63) == 0) red[o >> 6] = v;
    __syncthreads();
    if (o < B) {
        float base = red[0] + red[1];
        float tot = (float)partial[o] + base + fc_b[0];
        out[o] = 1.0f / (1.0f + expf(-tot));
    }
}

extern "C" void kernel_launch(void* const* d_in, const int* in_sizes, int n_in,
                              void* d_out, int out_size, void* d_ws, size_t ws_size,
                              hipStream_t stream) {
    const float* pos1   = (const float*)d_in[0];
    const float* pos2   = (const float*)d_in[1];
    const float* h1     = (const float*)d_in[2];
    const float* h2     = (const float*)d_in[3];
    const float* valid1 = (const float*)d_in[4];
    const float* valid2 = (const float*)d_in[5];
    const float* conv_w = (const float*)d_in[6];
    const float* conv_b = (const float*)d_in[7];
    const float* fc_w   = (const float*)d_in[8];
    const float* fc_b   = (const float*)d_in[9];
    float* out = (float*)d_out;

    char* ws = (char*)d_ws;
    float*  sub        = (float*)(ws + OFF_SUB);
    int*    winner     = (int*)  (ws + OFF_WIN);
    int*    slotGrid   = (int*)  (ws + OFF_SLOT);
    int*    activeGrid = (int*)  (ws + OFF_ACTG);
    int*    occCount   = (int*)  (ws + OFF_OCNT);
    int*    activeCount= (int*)  (ws + OFF_ACNT);
    int*    occCoords  = (int*)  (ws + OFF_OCC);
    int*    activeList = (int*)  (ws + OFF_ALST);
    float*  feats      = (float*)(ws + OFF_FEAT);
    float*  Wt         = (float*)(ws + OFF_WT);
    float*  chansum    = (float*)(ws + OFF_CSUM);
    double* partial    = (double*)(ws + OFF_PART);

    // per-call re-init (harness does not re-poison between replays)
    hipMemsetAsync(winner,     0xFF, SZ_WIN,  stream);
    hipMemsetAsync(slotGrid,   0xFF, SZ_SLOT, stream);
    hipMemsetAsync(activeGrid, 0x00, SZ_SLOT, stream);
    hipMemsetAsync(occCount,   0x00, B*4,     stream);
    hipMemsetAsync(activeCount,0x00, B*4,     stream);
    hipMemsetAsync(partial,    0x00, B*8,     stream);

    k_bbox<<<B, 64, 0, stream>>>(pos1, valid1, sub);
    k_scatter<<<(B*NP + 255)/256, 256, 0, stream>>>(pos1, valid1, pos2, valid2, sub, winner);
    k_claim<<<(B*NP + 255)/256, 256, 0, stream>>>(pos1, valid1, pos2, valid2, h1, h2,
                                                  sub, winner, slotGrid, occCount, occCoords, feats);
    k_dilate<<<(B*MAXOCC*27 + 255)/256, 256, 0, stream>>>(occCount, occCoords,
                                                          activeGrid, activeCount, activeList);
    k_wt<<<(27*F*C + 255)/256, 256, 0, stream>>>(conv_w, Wt);
    k_chansum<<<C, 256, 0, stream>>>(fc_w, chansum);
    k_conv<<<dim3(MAXACT, B), 128, 0, stream>>>(slotGrid, feats, activeList, activeCount,
                                                Wt, conv_b, fc_w, partial);
    k_final<<<1, 128, 0, stream>>>(chansum, conv_b, fc_b, partial, out);
}

// Round 2
// 2187.680 us; speedup vs baseline: 1.0216x; 1.0216x over previous
//
#include <hip/hip_runtime.h>
#include <float.h>
#include <math.h>

// Problem constants (fixed shapes from setup_inputs)
constexpr int B = 8, N1 = 400, N2 = 64, NP = N1 + N2, F = 54, C = 128;
constexpr int RR = 40;        // lattice size after slicing
constexpr int RG = 41;        // scatter grid (includes dump cell at 40,40,40)
constexpr int VOX = RR*RR*RR; // 64000
constexpr int MAXOCC = NP;            // max occupied voxels per batch
constexpr int MAXACT = NP * 27;       // max active (dilated) voxels per batch

constexpr size_t align256(size_t x) { return (x + 255) & ~(size_t)255; }

// Workspace layout
constexpr size_t OFF_SUB   = 0;                                   // B*3 f32
constexpr size_t OFF_WIN   = align256(OFF_SUB  + (size_t)B*3*4);  // B*41^3 i32
constexpr size_t SZ_WIN    = (size_t)B*RG*RG*RG*4;
constexpr size_t OFF_SLOT  = align256(OFF_WIN  + SZ_WIN);         // B*40^3 i32
constexpr size_t SZ_SLOT   = (size_t)B*VOX*4;
constexpr size_t OFF_ACNTG = align256(OFF_SLOT + SZ_SLOT);        // B*40^3 i32 contributor count
constexpr size_t OFF_AFST  = align256(OFF_ACNTG+ SZ_SLOT);        // B*40^3 i32 first contributor
constexpr size_t OFF_OCNT  = align256(OFF_AFST + SZ_SLOT);        // B i32
constexpr size_t OFF_ACNT  = align256(OFF_OCNT + (size_t)B*4);    // B i32
constexpr size_t OFF_OCC   = align256(OFF_ACNT + (size_t)B*4);    // B*MAXOCC i32
constexpr size_t OFF_ALST  = align256(OFF_OCC  + (size_t)B*MAXOCC*4); // B*MAXACT i32
constexpr size_t OFF_FEAT  = align256(OFF_ALST + (size_t)B*MAXACT*4); // B*MAXOCC*F f32
constexpr size_t OFF_WT    = align256(OFF_FEAT + (size_t)B*MAXOCC*F*4); // 27*F*C f32
constexpr size_t OFF_CSP   = align256(OFF_WT   + (size_t)27*F*C*4);     // C*16 f32
constexpr size_t OFF_PART  = align256(OFF_CSP  + (size_t)C*16*4);       // B f64
constexpr size_t OFF_FCT   = align256(OFF_PART + (size_t)B*8);          // VOX*C f32 (transposed fc_w)
constexpr size_t OFF_END   = OFF_FCT + (size_t)VOX*C*4;
constexpr size_t OFF_END_NOT= OFF_FCT;   // end of layout when transpose doesn't fit

// ---------------- K1: bounding-box center (sub) ----------------
__global__ void k_bbox(const float* __restrict__ pos1,
                       const float* __restrict__ valid1,
                       float* __restrict__ sub) {
    int b = blockIdx.x;
    int t = threadIdx.x;  // 64 threads = 1 wave
    float bmax[3] = {-FLT_MAX, -FLT_MAX, -FLT_MAX};
    float bmin[3] = { FLT_MAX,  FLT_MAX,  FLT_MAX};
    for (int n = t; n < N1; n += 64) {
        float v = valid1[b*N1 + n];
        const float* pp = pos1 + ((size_t)b*N1 + n)*3;
        float p0 = pp[0]*v, p1 = pp[1]*v, p2 = pp[2]*v;
        float s = p0 + p1 + p2;
        bool nz = (s == 0.0f);
        float amax = nz ? -10000000000.0f : 0.0f;
        float amin = nz ?  10000000000.0f : 0.0f;
        bmax[0] = fmaxf(bmax[0], p0 + amax);
        bmax[1] = fmaxf(bmax[1], p1 + amax);
        bmax[2] = fmaxf(bmax[2], p2 + amax);
        bmin[0] = fminf(bmin[0], p0 + amin);
        bmin[1] = fminf(bmin[1], p1 + amin);
        bmin[2] = fminf(bmin[2], p2 + amin);
    }
    #pragma unroll
    for (int off = 32; off; off >>= 1) {
        #pragma unroll
        for (int d = 0; d < 3; d++) {
            bmax[d] = fmaxf(bmax[d], __shfl_xor(bmax[d], off));
            bmin[d] = fminf(bmin[d], __shfl_xor(bmin[d], off));
        }
    }
    if (t == 0) {
        #pragma unroll
        for (int d = 0; d < 3; d++)
            sub[b*3 + d] = bmin[d] + (bmax[d] - bmin[d]) / 2.0f;
    }
}

// helper: compute voxel index for global point n (n<N1 -> pos1 else pos2)
__device__ inline void point_idx(const float* pos1, const float* valid1,
                                 const float* pos2, const float* valid2,
                                 const float* sub, int b, int n,
                                 int& ix, int& iy, int& iz, bool& inb, float& vout) {
    float px, py, pz, v;
    if (n < N1) {
        v = valid1[b*N1 + n];
        const float* p = pos1 + ((size_t)b*N1 + n)*3;
        px = p[0]*v; py = p[1]*v; pz = p[2]*v;
    } else {
        int m = n - N1;
        v = valid2[b*N2 + m];
        const float* p = pos2 + ((size_t)b*N2 + m)*3;
        px = p[0]*v; py = p[1]*v; pz = p[2]*v;
    }
    const float* sb = sub + b*3;
    ix = (int)floorf((px - sb[0] + 10.0f) / 0.5f);
    iy = (int)floorf((py - sb[1] + 10.0f) / 0.5f);
    iz = (int)floorf((pz - sb[2] + 10.0f) / 0.5f);
    inb = (ix >= 0 && ix <= RR-1 && iy >= 0 && iy <= RR-1 && iz >= 0 && iz <= RR-1);
    vout = v;
}

// ---------------- K2: winner scatter (last-write-wins via atomicMax) ----------------
__global__ void k_scatter(const float* __restrict__ pos1, const float* __restrict__ valid1,
                          const float* __restrict__ pos2, const float* __restrict__ valid2,
                          const float* __restrict__ sub, int* __restrict__ winner) {
    int g = blockIdx.x*blockDim.x + threadIdx.x;
    if (g >= B*NP) return;
    int b = g / NP, n = g % NP;
    int ix, iy, iz; bool inb; float v;
    point_idx(pos1, valid1, pos2, valid2, sub, b, n, ix, iy, iz, inb, v);
    int x = inb ? ix : RR, y = inb ? iy : RR, z = inb ? iz : RR;
    int cell = (x*RG + y)*RG + z;
    atomicMax(&winner[(size_t)b*RG*RG*RG + cell], n);
}

// ---------------- K3: claim winners, compact occupied list + features ----------------
__global__ void k_claim(const float* __restrict__ pos1, const float* __restrict__ valid1,
                        const float* __restrict__ pos2, const float* __restrict__ valid2,
                        const float* __restrict__ h1, const float* __restrict__ h2,
                        const float* __restrict__ sub, const int* __restrict__ winner,
                        int* __restrict__ slotGrid, int* __restrict__ occCount,
                        int* __restrict__ occCoords, float* __restrict__ feats) {
    int g = blockIdx.x*blockDim.x + threadIdx.x;
    if (g >= B*NP) return;
    int b = g / NP, n = g % NP;
    int ix, iy, iz; bool inb; float v;
    point_idx(pos1, valid1, pos2, valid2, sub, b, n, ix, iy, iz, inb, v);
    if (!inb) return;  // dump cell (40,40,40) is sliced off
    int cell = (ix*RG + iy)*RG + iz;
    if (winner[(size_t)b*RG*RG*RG + cell] != n) return;
    int slot = atomicAdd(&occCount[b], 1);
    slotGrid[(size_t)b*VOX + (ix*RR + iy)*RR + iz] = slot;
    occCoords[b*MAXOCC + slot] = (ix << 12) | (iy << 6) | iz;
    const float* h = (n < N1) ? (h1 + ((size_t)b*N1 + n)*F)
                              : (h2 + ((size_t)b*N2 + (n - N1))*F);
    float* fo = feats + ((size_t)b*MAXOCC + slot)*F;
    for (int f = 0; f < F; f++) fo[f] = h[f] * v;
}

// ---------------- K4: dilate occupied -> active list + contributor count/first ----------------
__global__ void k_dilate(const int* __restrict__ occCount, const int* __restrict__ occCoords,
                         int* __restrict__ actCnt, int* __restrict__ actFirst,
                         int* __restrict__ activeCount, int* __restrict__ activeList) {
    int g = blockIdx.x*blockDim.x + threadIdx.x;
    if (g >= B*MAXOCC*27) return;
    int b = g / (MAXOCC*27);
    int rem = g % (MAXOCC*27);
    int sl = rem / 27, k = rem % 27;
    if (sl >= occCount[b]) return;
    int pc = occCoords[b*MAXOCC + sl];
    int x = pc >> 12, y = (pc >> 6) & 63, z = pc & 63;
    int nx = x + k/9 - 1, ny = y + (k/3)%3 - 1, nz = z + k%3 - 1;
    if (nx < 0 || nx >= RR || ny < 0 || ny >= RR || nz < 0 || nz >= RR) return;
    size_t lin = (size_t)b*VOX + (nx*RR + ny)*RR + nz;
    int c = atomicAdd(&actCnt[lin], 1);
    if (c == 0) {
        int a = atomicAdd(&activeCount[b], 1);
        activeList[b*MAXACT + a] = (nx << 12) | (ny << 6) | nz;
    }
    // stencil index of THIS contributor as seen from the output voxel:
    // occupied - output = (-(dx), -(dy), -(dz)); probe convention s=(dp,dq,dr)
    // with occupied-output = (dp-1, 1-dq, 1-dr)  =>  dp=1-dx, dq=1+dy, dr=1+dz
    int sten = (2 - k/9)*9 + ((k/3)%3)*3 + (k%3);
    actFirst[lin] = (sl << 5) | sten;   // benign race; only read when actCnt==1
}

// ---------------- K5: transpose conv_w (O,F,27) -> Wt (27,F,O) ----------------
__global__ void k_wt(const float* __restrict__ conv_w, float* __restrict__ Wt) {
    int g = blockIdx.x*blockDim.x + threadIdx.x;
    if (g >= 27*F*C) return;
    int o = g & (C-1);
    int rest = g >> 7;       // C==128
    int f = rest % F, s = rest / F;
    Wt[g] = conv_w[((size_t)o*F + f)*27 + s];
}

// ---------------- K6: LDS-tiled transpose fc_w (C,VOX) -> fcT (VOX,C) ----------------
__global__ __launch_bounds__(256)
void k_fct(const float* __restrict__ fc_w, float* __restrict__ fcT) {
    __shared__ float tile[16][65];
    int v0 = blockIdx.x * 64;     // 1000
    int o0 = blockIdx.y * 16;     // 8
    int t = threadIdx.x;          // 256
    int tv = t & 63, to = t >> 6; // read 4 o-rows per iter, coalesced in v
    #pragma unroll
    for (int oo = 0; oo < 16; oo += 4)
        tile[to + oo][tv] = fc_w[(size_t)(o0 + to + oo)*VOX + v0 + tv];
    __syncthreads();
    int to2 = t & 15, tv2 = t >> 4; // write 16 v-rows per iter, coalesced in o
    #pragma unroll
    for (int vv = 0; vv < 64; vv += 16)
        fcT[(size_t)(v0 + tv2 + vv)*C + o0 + to2] = tile[to2][tv2 + vv];
}

// ---------------- K7: per-channel fc_w partial sums (deterministic) ----------------
__global__ void k_cspart(const float* __restrict__ fc_w, float* __restrict__ csPart) {
    int seg = blockIdx.x;  // 16
    int o   = blockIdx.y;  // 128
    const float* p = fc_w + (size_t)o*VOX + seg*4000;
    float s = 0.0f;
    for (int i = threadIdx.x; i < 4000; i += 256) s += p[i];
    #pragma unroll
    for (int off = 32; off; off >>= 1) s += __shfl_xor(s, off);
    __shared__ float red[4];
    if ((threadIdx.x & 63) == 0) red[threadIdx.x >> 6] = s;
    __syncthreads();
    if (threadIdx.x == 0) csPart[o*16 + seg] = red[0] + red[1] + red[2] + red[3];
}

// ---------------- K8: sparse conv + relu-diff + fc dot, per active voxel ----------------
__global__ __launch_bounds__(128)
void k_conv(const int* __restrict__ slotGrid, const float* __restrict__ feats,
            const int* __restrict__ activeList, const int* __restrict__ activeCount,
            const int* __restrict__ actCnt, const int* __restrict__ actFirst,
            const float* __restrict__ Wt, const float* __restrict__ conv_b,
            const float* __restrict__ fcT, const float* __restrict__ fc_w, int useT,
            double* __restrict__ partial) {
    int b = blockIdx.y;
    int a = blockIdx.x;
    if (a >= activeCount[b]) return;
    int o = threadIdx.x;  // channel

    __shared__ int ns;
    __shared__ int slist[27];
    __shared__ int sstencil[27];

    int pc = activeList[b*MAXACT + a];
    int x0 = pc >> 12, y0 = (pc >> 6) & 63, z0 = pc & 63;
    size_t lin = (size_t)b*VOX + (x0*RR + y0)*RR + z0;
    int cnt = actCnt[lin];

    float acc = 0.0f;
    if (cnt == 1) {
        // fast path: single contributor recorded by k_dilate
        int info = actFirst[lin];
        int sl = info >> 5, st = info & 31;
        const float* fv = feats + ((size_t)b*MAXOCC + sl)*F;
        const float* wv = Wt + (size_t)st*F*C + o;
        #pragma unroll
        for (int f = 0; f < F; f++) acc = fmaf(fv[f], wv[(size_t)f*C], acc);
    } else {
        if (o == 0) ns = 0;
        __syncthreads();
        if (o < 27) {
            int dp = o/9, dq = (o/3)%3, dr = o%3;
            int nx = x0 + dp - 1, ny = y0 + 1 - dq, nz = z0 + 1 - dr;
            if (nx >= 0 && nx < RR && ny >= 0 && ny < RR && nz >= 0 && nz < RR) {
                int sl = slotGrid[(size_t)b*VOX + (nx*RR + ny)*RR + nz];
                if (sl >= 0) { int p = atomicAdd(&ns, 1); slist[p] = sl; sstencil[p] = o; }
            }
        }
        __syncthreads();
        int n = ns;
        for (int e = 0; e < n; e++) {
            int sl = slist[e], st = sstencil[e];
            const float* fv = feats + ((size_t)b*MAXOCC + sl)*F;
            const float* wv = Wt + (size_t)st*F*C + o;
            #pragma unroll
            for (int f = 0; f < F; f++) acc = fmaf(fv[f], wv[(size_t)f*C], acc);
        }
    }
    float bo = conv_b[o];
    float outv = fmaxf(acc + bo, 0.0f) - fmaxf(bo, 0.0f);
    int flat = x0*1600 + (RR-1 - y0)*RR + (RR-1 - z0);
    float w = useT ? fcT[(size_t)flat*C + o] : fc_w[(size_t)o*VOX + flat];
    float csum = outv * w;

    #pragma unroll
    for (int off = 32; off; off >>= 1) csum += __shfl_xor(csum, off);
    __shared__ float wsum[2];
    if ((o & 63) == 0) wsum[o >> 6] = csum;
    __syncthreads();
    if (o == 0) atomicAdd(&partial[b], (double)(wsum[0] + wsum[1]));
}

// ---------------- K9: finalize ----------------
__global__ void k_final(const float* __restrict__ csPart, const float* __restrict__ conv_b,
                        const float* __restrict__ fc_b, const double* __restrict__ partial,
                        float* __restrict__ out) {
    int o = threadIdx.x;  // 128 threads
    float cs = 0.0f;
    #pragma unroll
    for (int k = 0; k < 16; k++) cs += csPart[o*16 + k];
    float v = fmaxf(conv_b[o], 0.0f) * cs;
    #pragma unroll
    for (int off = 32; off; off >>= 1) v += __shfl_xor(v, off);
    __shared__ float red[2];
    if ((o & 63) == 0) red[o >> 6] = v;
    __syncthreads();
    if (o < B) {
        float base = red[0] + red[1];
        float tot = (float)partial[o] + base + fc_b[0];
        out[o] = 1.0f / (1.0f + expf(-tot));
    }
}

extern "C" void kernel_launch(void* const* d_in, const int* in_sizes, int n_in,
                              void* d_out, int out_size, void* d_ws, size_t ws_size,
                              hipStream_t stream) {
    const float* pos1   = (const float*)d_in[0];
    const float* pos2   = (const float*)d_in[1];
    const float* h1     = (const float*)d_in[2];
    const float* h2     = (const float*)d_in[3];
    const float* valid1 = (const float*)d_in[4];
    const float* valid2 = (const float*)d_in[5];
    const float* conv_w = (const float*)d_in[6];
    const float* conv_b = (const float*)d_in[7];
    const float* fc_w   = (const float*)d_in[8];
    const float* fc_b   = (const float*)d_in[9];
    float* out = (float*)d_out;

    char* ws = (char*)d_ws;
    float*  sub        = (float*)(ws + OFF_SUB);
    int*    winner     = (int*)  (ws + OFF_WIN);
    int*    slotGrid   = (int*)  (ws + OFF_SLOT);
    int*    actCnt     = (int*)  (ws + OFF_ACNTG);
    int*    actFirst   = (int*)  (ws + OFF_AFST);
    int*    occCount   = (int*)  (ws + OFF_OCNT);
    int*    activeCount= (int*)  (ws + OFF_ACNT);
    int*    occCoords  = (int*)  (ws + OFF_OCC);
    int*    activeList = (int*)  (ws + OFF_ALST);
    float*  feats      = (float*)(ws + OFF_FEAT);
    float*  Wt         = (float*)(ws + OFF_WT);
    float*  csPart     = (float*)(ws + OFF_CSP);
    double* partial    = (double*)(ws + OFF_PART);
    float*  fcT        = (float*)(ws + OFF_FCT);

    const int useT = (ws_size >= OFF_END) ? 1 : 0;

    // per-call re-init (harness does not re-poison between replays)
    hipMemsetAsync(winner,     0xFF, SZ_WIN,  stream);
    hipMemsetAsync(slotGrid,   0xFF, SZ_SLOT, stream);
    hipMemsetAsync(actCnt,     0x00, SZ_SLOT, stream);
    hipMemsetAsync(occCount,   0x00, B*4,     stream);
    hipMemsetAsync(activeCount,0x00, B*4,     stream);
    hipMemsetAsync(partial,    0x00, B*8,     stream);

    k_bbox<<<B, 64, 0, stream>>>(pos1, valid1, sub);
    k_scatter<<<(B*NP + 255)/256, 256, 0, stream>>>(pos1, valid1, pos2, valid2, sub, winner);
    k_claim<<<(B*NP + 255)/256, 256, 0, stream>>>(pos1, valid1, pos2, valid2, h1, h2,
                                                  sub, winner, slotGrid, occCount, occCoords, feats);
    k_dilate<<<(B*MAXOCC*27 + 255)/256, 256, 0, stream>>>(occCount, occCoords,
                                                          actCnt, actFirst, activeCount, activeList);
    k_wt<<<(27*F*C + 255)/256, 256, 0, stream>>>(conv_w, Wt);
    if (useT)
        k_fct<<<dim3(VOX/64, C/16), 256, 0, stream>>>(fc_w, fcT);
    k_cspart<<<dim3(16, C), 256, 0, stream>>>(fc_w, csPart);
    k_conv<<<dim3(MAXACT, B), 128, 0, stream>>>(slotGrid, feats, activeList, activeCount,
                                                actCnt, actFirst, Wt, conv_b, fcT, fc_w, useT, partial);
    k_final<<<1, 128, 0, stream>>>(csPart, conv_b, fc_b, partial, out);
}

// Round 3
// 179.458 us; speedup vs baseline: 12.4534x; 12.1905x over previous
//
#include <hip/hip_runtime.h>
#include <float.h>
#include <math.h>

// Problem constants (fixed shapes from setup_inputs)
constexpr int B = 8, N1 = 400, N2 = 64, NP = N1 + N2, F = 54, C = 128;
constexpr int RR = 40;        // lattice size after slicing
constexpr int RG = 41;        // scatter grid (includes dump cell at 40,40,40)
constexpr int VOX = RR*RR*RR; // 64000
constexpr int MAXOCC = NP;            // max occupied voxels per batch
constexpr int MAXACT = NP * 27;       // grid size for conv blocks (one per occ x stencil)

constexpr size_t align256(size_t x) { return (x + 255) & ~(size_t)255; }

// Workspace layout
constexpr size_t OFF_SUB   = 0;                                   // B*3 f32
constexpr size_t OFF_WIN   = align256(OFF_SUB  + (size_t)B*3*4);  // B*41^3 i32
constexpr size_t SZ_WIN    = (size_t)B*RG*RG*RG*4;
constexpr size_t OFF_SLOT  = align256(OFF_WIN  + SZ_WIN);         // B*40^3 i32
constexpr size_t SZ_SLOT   = (size_t)B*VOX*4;
constexpr size_t OFF_ACNTG = align256(OFF_SLOT + SZ_SLOT);        // B*40^3 i32 contributor count
constexpr size_t OFF_AFST  = align256(OFF_ACNTG+ SZ_SLOT);        // B*40^3 u32 owner (min packed id)
constexpr size_t OFF_OCNT  = align256(OFF_AFST + SZ_SLOT);        // B*16 i32 (padded, 1 line/batch)
constexpr size_t OFF_OCC   = align256(OFF_OCNT + (size_t)B*16*4); // B*MAXOCC i32
constexpr size_t OFF_FEAT  = align256(OFF_OCC  + (size_t)B*MAXOCC*4); // B*MAXOCC*F f32
constexpr size_t OFF_WT    = align256(OFF_FEAT + (size_t)B*MAXOCC*F*4); // 27*F*C f32
constexpr size_t OFF_CSP   = align256(OFF_WT   + (size_t)27*F*C*4);     // C*16 f32
constexpr size_t OFF_BSUM  = align256(OFF_CSP  + (size_t)C*16*4);       // B*MAXACT f32
constexpr size_t OFF_FCT   = align256(OFF_BSUM + (size_t)B*MAXACT*4);   // VOX*C f32
constexpr size_t OFF_END   = OFF_FCT + (size_t)VOX*C*4;

// ---------------- K1: bounding-box center (sub) ----------------
__global__ void k_bbox(const float* __restrict__ pos1,
                       const float* __restrict__ valid1,
                       float* __restrict__ sub) {
    int b = blockIdx.x;
    int t = threadIdx.x;  // 64 threads = 1 wave
    float bmax[3] = {-FLT_MAX, -FLT_MAX, -FLT_MAX};
    float bmin[3] = { FLT_MAX,  FLT_MAX,  FLT_MAX};
    for (int n = t; n < N1; n += 64) {
        float v = valid1[b*N1 + n];
        const float* pp = pos1 + ((size_t)b*N1 + n)*3;
        float p0 = pp[0]*v, p1 = pp[1]*v, p2 = pp[2]*v;
        float s = p0 + p1 + p2;
        bool nz = (s == 0.0f);
        float amax = nz ? -10000000000.0f : 0.0f;
        float amin = nz ?  10000000000.0f : 0.0f;
        bmax[0] = fmaxf(bmax[0], p0 + amax);
        bmax[1] = fmaxf(bmax[1], p1 + amax);
        bmax[2] = fmaxf(bmax[2], p2 + amax);
        bmin[0] = fminf(bmin[0], p0 + amin);
        bmin[1] = fminf(bmin[1], p1 + amin);
        bmin[2] = fminf(bmin[2], p2 + amin);
    }
    #pragma unroll
    for (int off = 32; off; off >>= 1) {
        #pragma unroll
        for (int d = 0; d < 3; d++) {
            bmax[d] = fmaxf(bmax[d], __shfl_xor(bmax[d], off));
            bmin[d] = fminf(bmin[d], __shfl_xor(bmin[d], off));
        }
    }
    if (t == 0) {
        #pragma unroll
        for (int d = 0; d < 3; d++)
            sub[b*3 + d] = bmin[d] + (bmax[d] - bmin[d]) / 2.0f;
    }
}

// helper: compute voxel index for global point n (n<N1 -> pos1 else pos2)
__device__ inline void point_idx(const float* pos1, const float* valid1,
                                 const float* pos2, const float* valid2,
                                 const float* sub, int b, int n,
                                 int& ix, int& iy, int& iz, bool& inb, float& vout) {
    float px, py, pz, v;
    if (n < N1) {
        v = valid1[b*N1 + n];
        const float* p = pos1 + ((size_t)b*N1 + n)*3;
        px = p[0]*v; py = p[1]*v; pz = p[2]*v;
    } else {
        int m = n - N1;
        v = valid2[b*N2 + m];
        const float* p = pos2 + ((size_t)b*N2 + m)*3;
        px = p[0]*v; py = p[1]*v; pz = p[2]*v;
    }
    const float* sb = sub + b*3;
    ix = (int)floorf((px - sb[0] + 10.0f) / 0.5f);
    iy = (int)floorf((py - sb[1] + 10.0f) / 0.5f);
    iz = (int)floorf((pz - sb[2] + 10.0f) / 0.5f);
    inb = (ix >= 0 && ix <= RR-1 && iy >= 0 && iy <= RR-1 && iz >= 0 && iz <= RR-1);
    vout = v;
}

// ---------------- K2: winner scatter (last-write-wins via atomicMax) ----------------
__global__ void k_scatter(const float* __restrict__ pos1, const float* __restrict__ valid1,
                          const float* __restrict__ pos2, const float* __restrict__ valid2,
                          const float* __restrict__ sub, int* __restrict__ winner) {
    int g = blockIdx.x*blockDim.x + threadIdx.x;
    if (g >= B*NP) return;
    int b = g / NP, n = g % NP;
    int ix, iy, iz; bool inb; float v;
    point_idx(pos1, valid1, pos2, valid2, sub, b, n, ix, iy, iz, inb, v);
    int x = inb ? ix : RR, y = inb ? iy : RR, z = inb ? iz : RR;
    int cell = (x*RG + y)*RG + z;
    atomicMax(&winner[(size_t)b*RG*RG*RG + cell], n);
}

// ---------------- K3: claim winners, compact occupied list + features ----------------
__global__ void k_claim(const float* __restrict__ pos1, const float* __restrict__ valid1,
                        const float* __restrict__ pos2, const float* __restrict__ valid2,
                        const float* __restrict__ h1, const float* __restrict__ h2,
                        const float* __restrict__ sub, const int* __restrict__ winner,
                        int* __restrict__ slotGrid, int* __restrict__ occCount,
                        int* __restrict__ occCoords, float* __restrict__ feats) {
    int g = blockIdx.x*blockDim.x + threadIdx.x;
    if (g >= B*NP) return;
    int b = g / NP, n = g % NP;
    int ix, iy, iz; bool inb; float v;
    point_idx(pos1, valid1, pos2, valid2, sub, b, n, ix, iy, iz, inb, v);
    if (!inb) return;  // dump cell (40,40,40) is sliced off
    int cell = (ix*RG + iy)*RG + iz;
    if (winner[(size_t)b*RG*RG*RG + cell] != n) return;
    int slot = atomicAdd(&occCount[b*16], 1);
    slotGrid[(size_t)b*VOX + (ix*RR + iy)*RR + iz] = slot;
    occCoords[b*MAXOCC + slot] = (ix << 12) | (iy << 6) | iz;
    const float* h = (n < N1) ? (h1 + ((size_t)b*N1 + n)*F)
                              : (h2 + ((size_t)b*N2 + (n - N1))*F);
    float* fo = feats + ((size_t)b*MAXOCC + slot)*F;
    for (int f = 0; f < F; f++) fo[f] = h[f] * v;
}

// ---------------- K4: dilate -> contributor count + deterministic owner (atomicMin) ----------------
__global__ void k_dilate(const int* __restrict__ occCount, const int* __restrict__ occCoords,
                         int* __restrict__ actCnt, unsigned* __restrict__ actFirst) {
    int g = blockIdx.x*blockDim.x + threadIdx.x;
    if (g >= B*MAXOCC*27) return;
    int b = g / (MAXOCC*27);
    int rem = g % (MAXOCC*27);
    int sl = rem / 27, k = rem % 27;
    if (sl >= occCount[b*16]) return;
    int pc = occCoords[b*MAXOCC + sl];
    int x = pc >> 12, y = (pc >> 6) & 63, z = pc & 63;
    int nx = x + k/9 - 1, ny = y + (k/3)%3 - 1, nz = z + k%3 - 1;
    if (nx < 0 || nx >= RR || ny < 0 || ny >= RR || nz < 0 || nz >= RR) return;
    size_t lin = (size_t)b*VOX + (nx*RR + ny)*RR + nz;
    atomicAdd(&actCnt[lin], 1);
    // stencil index of THIS contributor as seen from the output voxel:
    // occupied - output = (1-k/9, 1-(k/3)%3, 1-k%3) = (dp-1, 1-dq, 1-dr)
    int sten = (2 - k/9)*9 + ((k/3)%3)*3 + (k%3);
    atomicMin(&actFirst[lin], ((unsigned)sl << 5) | (unsigned)sten);
}

// ---------------- K5: transpose conv_w (O,F,27) -> Wt (27,F,O) ----------------
__global__ void k_wt(const float* __restrict__ conv_w, float* __restrict__ Wt) {
    int g = blockIdx.x*blockDim.x + threadIdx.x;
    if (g >= 27*F*C) return;
    int o = g & (C-1);
    int rest = g >> 7;       // C==128
    int f = rest % F, s = rest / F;
    Wt[g] = conv_w[((size_t)o*F + f)*27 + s];
}

// ---------------- K6: LDS-tiled transpose fc_w (C,VOX) -> fcT (VOX,C) ----------------
__global__ __launch_bounds__(256)
void k_fct(const float* __restrict__ fc_w, float* __restrict__ fcT) {
    __shared__ float tile[16][65];
    int v0 = blockIdx.x * 64;     // 1000
    int o0 = blockIdx.y * 16;     // 8
    int t = threadIdx.x;          // 256
    int tv = t & 63, to = t >> 6; // read 4 o-rows per iter, coalesced in v
    #pragma unroll
    for (int oo = 0; oo < 16; oo += 4)
        tile[to + oo][tv] = fc_w[(size_t)(o0 + to + oo)*VOX + v0 + tv];
    __syncthreads();
    int to2 = t & 15, tv2 = t >> 4; // write 16 v-rows per iter, coalesced in o
    #pragma unroll
    for (int vv = 0; vv < 64; vv += 16)
        fcT[(size_t)(v0 + tv2 + vv)*C + o0 + to2] = tile[to2][tv2 + vv];
}

// ---------------- K7: per-channel fc_w partial sums (deterministic) ----------------
__global__ void k_cspart(const float* __restrict__ fc_w, float* __restrict__ csPart) {
    int seg = blockIdx.x;  // 16
    int o   = blockIdx.y;  // 128
    const float* p = fc_w + (size_t)o*VOX + seg*4000;
    float s = 0.0f;
    for (int i = threadIdx.x; i < 4000; i += 256) s += p[i];
    #pragma unroll
    for (int off = 32; off; off >>= 1) s += __shfl_xor(s, off);
    __shared__ float red[4];
    if ((threadIdx.x & 63) == 0) red[threadIdx.x >> 6] = s;
    __syncthreads();
    if (threadIdx.x == 0) csPart[o*16 + seg] = red[0] + red[1] + red[2] + red[3];
}

// ---------------- K8: sparse conv, one block per (occupied,stencil); owner computes voxel ----------------
__global__ __launch_bounds__(128)
void k_conv(const int* __restrict__ slotGrid, const float* __restrict__ feats,
            const int* __restrict__ occCount, const int* __restrict__ occCoords,
            const int* __restrict__ actCnt, const unsigned* __restrict__ actFirst,
            const float* __restrict__ Wt, const float* __restrict__ conv_b,
            const float* __restrict__ fcT, const float* __restrict__ fc_w, int useT,
            float* __restrict__ blockSums) {
    int b = blockIdx.y;
    int a = blockIdx.x;   // a = s*27 + k
    int o = threadIdx.x;  // channel

    int s = a / 27, k = a % 27;
    bool active = (s < occCount[b*16]);
    int x0 = 0, y0 = 0, z0 = 0;
    if (active) {
        int pc = occCoords[b*MAXOCC + s];
        int x = pc >> 12, y = (pc >> 6) & 63, z = pc & 63;
        x0 = x + k/9 - 1; y0 = y + (k/3)%3 - 1; z0 = z + k%3 - 1;
        if (x0 < 0 || x0 >= RR || y0 < 0 || y0 >= RR || z0 < 0 || z0 >= RR) active = false;
    }
    size_t lin = 0;
    int mySten = (2 - k/9)*9 + ((k/3)%3)*3 + (k%3);
    if (active) {
        lin = (size_t)b*VOX + (x0*RR + y0)*RR + z0;
        unsigned myid = ((unsigned)s << 5) | (unsigned)mySten;
        if (actFirst[lin] != myid) active = false;  // not the owner of this output voxel
    }
    if (!active) {
        if (o == 0) blockSums[(size_t)b*MAXACT + a] = 0.0f;
        return;
    }

    float acc = 0.0f;
    int cnt = actCnt[lin];
    if (cnt == 1) {
        // sole contributor is this block's own (s, mySten)
        const float* fv = feats + ((size_t)b*MAXOCC + s)*F;
        const float* wv = Wt + (size_t)mySten*F*C + o;
        #pragma unroll
        for (int f = 0; f < F; f++) acc = fmaf(fv[f], wv[(size_t)f*C], acc);
    } else {
        __shared__ int ns;
        __shared__ int slist[27];
        __shared__ int sstencil[27];
        if (o == 0) ns = 0;
        __syncthreads();
        if (o < 27) {
            int dp = o/9, dq = (o/3)%3, dr = o%3;
            int nx = x0 + dp - 1, ny = y0 + 1 - dq, nz = z0 + 1 - dr;
            if (nx >= 0 && nx < RR && ny >= 0 && ny < RR && nz >= 0 && nz < RR) {
                int sl = slotGrid[(size_t)b*VOX + (nx*RR + ny)*RR + nz];
                if (sl >= 0) { int p = atomicAdd(&ns, 1); slist[p] = sl; sstencil[p] = o; }
            }
        }
        __syncthreads();
        int n = ns;
        for (int e = 0; e < n; e++) {
            int sl = slist[e], st = sstencil[e];
            const float* fv = feats + ((size_t)b*MAXOCC + sl)*F;
            const float* wv = Wt + (size_t)st*F*C + o;
            #pragma unroll
            for (int f = 0; f < F; f++) acc = fmaf(fv[f], wv[(size_t)f*C], acc);
        }
    }
    float bo = conv_b[o];
    float outv = fmaxf(acc + bo, 0.0f) - fmaxf(bo, 0.0f);
    int flat = x0*1600 + (RR-1 - y0)*RR + (RR-1 - z0);
    float w = useT ? fcT[(size_t)flat*C + o] : fc_w[(size_t)o*VOX + flat];
    float csum = outv * w;

    #pragma unroll
    for (int off = 32; off; off >>= 1) csum += __shfl_xor(csum, off);
    __shared__ float wsum[2];
    if ((o & 63) == 0) wsum[o >> 6] = csum;
    __syncthreads();
    if (o == 0) blockSums[(size_t)b*MAXACT + a] = wsum[0] + wsum[1];
}

// ---------------- K9: deterministic per-batch reduce + background + sigmoid ----------------
__global__ __launch_bounds__(256)
void k_reduce(const float* __restrict__ blockSums, const float* __restrict__ csPart,
              const float* __restrict__ conv_b, const float* __restrict__ fc_b,
              float* __restrict__ out) {
    int b = blockIdx.x;
    int t = threadIdx.x;  // 256
    float s = 0.0f;
    for (int i = t; i < MAXACT; i += 256) s += blockSums[(size_t)b*MAXACT + i];
    for (int i = t; i < C*16; i += 256) s += fmaxf(conv_b[i >> 4], 0.0f) * csPart[i];
    #pragma unroll
    for (int off = 32; off; off >>= 1) s += __shfl_xor(s, off);
    __shared__ float red[4];
    if ((t & 63) == 0) red[t >> 6] = s;
    __syncthreads();
    if (t == 0) {
        float tot = red[0] + red[1] + red[2] + red[3] + fc_b[0];
        out[b] = 1.0f / (1.0f + expf(-tot));
    }
}

extern "C" void kernel_launch(void* const* d_in, const int* in_sizes, int n_in,
                              void* d_out, int out_size, void* d_ws, size_t ws_size,
                              hipStream_t stream) {
    const float* pos1   = (const float*)d_in[0];
    const float* pos2   = (const float*)d_in[1];
    const float* h1     = (const float*)d_in[2];
    const float* h2     = (const float*)d_in[3];
    const float* valid1 = (const float*)d_in[4];
    const float* valid2 = (const float*)d_in[5];
    const float* conv_w = (const float*)d_in[6];
    const float* conv_b = (const float*)d_in[7];
    const float* fc_w   = (const float*)d_in[8];
    const float* fc_b   = (const float*)d_in[9];
    float* out = (float*)d_out;

    char* ws = (char*)d_ws;
    float*    sub      = (float*)   (ws + OFF_SUB);
    int*      winner   = (int*)     (ws + OFF_WIN);
    int*      slotGrid = (int*)     (ws + OFF_SLOT);
    int*      actCnt   = (int*)     (ws + OFF_ACNTG);
    unsigned* actFirst = (unsigned*)(ws + OFF_AFST);
    int*      occCount = (int*)     (ws + OFF_OCNT);
    int*      occCoords= (int*)     (ws + OFF_OCC);
    float*    feats    = (float*)   (ws + OFF_FEAT);
    float*    Wt       = (float*)   (ws + OFF_WT);
    float*    csPart   = (float*)   (ws + OFF_CSP);
    float*    blockSums= (float*)   (ws + OFF_BSUM);
    float*    fcT      = (float*)   (ws + OFF_FCT);

    const int useT = (ws_size >= OFF_END) ? 1 : 0;

    // per-call re-init (harness does not re-poison between replays)
    hipMemsetAsync(winner,   0xFF, SZ_WIN,  stream);
    hipMemsetAsync(slotGrid, 0xFF, SZ_SLOT, stream);
    hipMemsetAsync(actCnt,   0x00, SZ_SLOT, stream);
    hipMemsetAsync(actFirst, 0xFF, SZ_SLOT, stream);
    hipMemsetAsync(occCount, 0x00, B*16*4,  stream);

    k_bbox<<<B, 64, 0, stream>>>(pos1, valid1, sub);
    k_scatter<<<(B*NP + 255)/256, 256, 0, stream>>>(pos1, valid1, pos2, valid2, sub, winner);
    k_claim<<<(B*NP + 255)/256, 256, 0, stream>>>(pos1, valid1, pos2, valid2, h1, h2,
                                                  sub, winner, slotGrid, occCount, occCoords, feats);
    k_dilate<<<(B*MAXOCC*27 + 255)/256, 256, 0, stream>>>(occCount, occCoords, actCnt, actFirst);
    k_wt<<<(27*F*C + 255)/256, 256, 0, stream>>>(conv_w, Wt);
    if (useT)
        k_fct<<<dim3(VOX/64, C/16), 256, 0, stream>>>(fc_w, fcT);
    k_cspart<<<dim3(16, C), 256, 0, stream>>>(fc_w, csPart);
    k_conv<<<dim3(MAXACT, B), 128, 0, stream>>>(slotGrid, feats, occCount, occCoords,
                                                actCnt, actFirst, Wt, conv_b, fcT, fc_w, useT,
                                                blockSums);
    k_reduce<<<B, 256, 0, stream>>>(blockSums, csPart, conv_b, fc_b, out);
}